// Round 1
// baseline (1063.770 us; speedup 1.0000x reference)
//
#include <hip/hip_runtime.h>

#define BATCH 2048
#define DIM   256

// Per-layer dense step, fully unrolled so activations stay in registers and
// weight loads (wave-uniform address) become s_load + SGPR-operand v_fma.
template <int FI, int FO, bool RELU>
__device__ __forceinline__ void layer(const float* __restrict__ W,
                                      const float* __restrict__ B,
                                      const float (&in)[FI], float (&out)[FO]) {
#pragma unroll
  for (int o = 0; o < FO; ++o) out[o] = B[o];
#pragma unroll
  for (int i = 0; i < FI; ++i) {
    const float h = in[i];
#pragma unroll
    for (int o = 0; o < FO; ++o) out[o] = fmaf(h, W[i * FO + o], out[o]);
  }
  if (RELU) {
#pragma unroll
    for (int o = 0; o < FO; ++o) out[o] = fmaxf(out[o], 0.0f);
  }
}

// One block = one feature dim d (uniform -> scalar weight loads), 256 batch rows.
__global__ __launch_bounds__(256, 2) void mlp_kernel(
    const float* __restrict__ x,
    const float* __restrict__ W0, const float* __restrict__ b0,
    const float* __restrict__ W1, const float* __restrict__ b1,
    const float* __restrict__ W2, const float* __restrict__ b2,
    const float* __restrict__ W3, const float* __restrict__ b3,
    const float* __restrict__ W4, const float* __restrict__ b4,
    const float* __restrict__ W5, const float* __restrict__ b5,
    const float* __restrict__ W6, const float* __restrict__ b6,
    float* __restrict__ partial) {
  const int d = blockIdx.x;                       // 0..255 (wave-uniform)
  const int b = blockIdx.y * 256 + threadIdx.x;   // 0..2047

  const float xv = x[b * DIM + d];

  // Layer 0: 1 -> 32
  float h1[32];
  {
    const float* W = W0 + d * 32;  // W0[d, 0, o]
    const float* B = b0 + d * 32;
#pragma unroll
    for (int o = 0; o < 32; ++o) h1[o] = fmaxf(fmaf(xv, W[o], B[o]), 0.0f);
  }

  float h2[64];
  layer<32, 64, true>(W1 + d * 32 * 64, b1 + d * 64, h1, h2);
  float h3[128];
  layer<64, 128, true>(W2 + d * 64 * 128, b2 + d * 128, h2, h3);
  float h4[64];
  layer<128, 64, true>(W3 + d * 128 * 64, b3 + d * 64, h3, h4);
  float h5[32];
  layer<64, 32, true>(W4 + d * 64 * 32, b4 + d * 32, h4, h5);
  float h6[16];
  layer<32, 16, true>(W5 + d * 32 * 16, b5 + d * 16, h5, h6);
  float h7[1];
  layer<16, 1, false>(W6 + d * 16, b6 + d, h6, h7);

  // Coalesced store: consecutive threads (consecutive b) -> consecutive addrs.
  partial[d * BATCH + b] = h7[0];
}

// Sum partials over d. Loads are coalesced across threads each iteration.
__global__ __launch_bounds__(256) void reduce_kernel(
    const float* __restrict__ partial, float* __restrict__ out) {
  const int b = blockIdx.x * blockDim.x + threadIdx.x;
  float s = 0.0f;
#pragma unroll 8
  for (int d = 0; d < DIM; ++d) s += partial[d * BATCH + b];
  out[b] = s;
}

extern "C" void kernel_launch(void* const* d_in, const int* in_sizes, int n_in,
                              void* d_out, int out_size, void* d_ws, size_t ws_size,
                              hipStream_t stream) {
  const float* x = (const float*)d_in[0];
  const float* W[7];
  const float* B[7];
  for (int l = 0; l < 7; ++l) {
    W[l] = (const float*)d_in[1 + 2 * l];
    B[l] = (const float*)d_in[2 + 2 * l];
  }
  float* partial = (float*)d_ws;  // DIM * BATCH floats = 2 MB

  dim3 grid(DIM, BATCH / 256);
  mlp_kernel<<<grid, dim3(256), 0, stream>>>(
      x, W[0], B[0], W[1], B[1], W[2], B[2], W[3], B[3], W[4], B[4], W[5], B[5],
      W[6], B[6], partial);

  reduce_kernel<<<dim3(BATCH / 256), dim3(256), 0, stream>>>(partial,
                                                             (float*)d_out);
}

// Round 3
// 767.495 us; speedup vs baseline: 1.3860x; 1.3860x over previous
//
#include <hip/hip_runtime.h>

#define BATCH 2048
#define DIM   256

// Dense layer, fully unrolled; weight addresses are wave-uniform -> scalar
// loads (s_load_dwordx16) + SGPR-operand v_fma.
template <int FI, int FO, bool RELU>
__device__ __forceinline__ void layer(const float* __restrict__ W,
                                      const float* __restrict__ B,
                                      const float (&in)[FI], float (&out)[FO]) {
#pragma unroll
  for (int o = 0; o < FO; ++o) out[o] = B[o];
#pragma unroll
  for (int i = 0; i < FI; ++i) {
    const float h = in[i];
#pragma unroll
    for (int o = 0; o < FO; ++o) out[o] = fmaf(h, W[i * FO + o], out[o]);
  }
  if (RELU) {
#pragma unroll
    for (int o = 0; o < FO; ++o) out[o] = fmaxf(out[o], 0.0f);
  }
}

// One block = one feature dim d (wave-uniform weights), 256 batch rows.
// Middle layers 64->128->64 are fused in chunks of 16 so the 128-wide
// activation never exists as a live array: peak live = 64+64+16 = 144 floats.
__global__ __launch_bounds__(256, 1) void mlp_kernel(
    const float* __restrict__ x,
    const float* __restrict__ W0, const float* __restrict__ b0,
    const float* __restrict__ W1, const float* __restrict__ b1,
    const float* __restrict__ W2, const float* __restrict__ b2,
    const float* __restrict__ W3, const float* __restrict__ b3,
    const float* __restrict__ W4, const float* __restrict__ b4,
    const float* __restrict__ W5, const float* __restrict__ b5,
    const float* __restrict__ W6, const float* __restrict__ b6,
    float* __restrict__ partial) {
  const int d = blockIdx.x;                       // 0..255 (wave-uniform)
  const int b = blockIdx.y * 256 + threadIdx.x;   // 0..2047

  const float xv = x[b * DIM + d];

  // Layer 0: 1 -> 32
  float h1[32];
  {
    const float* W = W0 + d * 32;
    const float* B = b0 + d * 32;
#pragma unroll
    for (int o = 0; o < 32; ++o) h1[o] = fmaxf(fmaf(xv, W[o], B[o]), 0.0f);
  }

  // Layer 1: 32 -> 64
  float h2[64];
  layer<32, 64, true>(W1 + d * 32 * 64, b1 + d * 64, h1, h2);

  // Layers 2+3 fused: 64 -> 128 -> 64, h3 processed in chunks of 16.
  float h4[64];
  {
    const float* W2d = W2 + d * 64 * 128;
    const float* b2d = b2 + d * 128;
    const float* W3d = W3 + d * 128 * 64;
    const float* b3d = b3 + d * 64;
#pragma unroll
    for (int o = 0; o < 64; ++o) h4[o] = b3d[o];
#pragma unroll
    for (int c = 0; c < 128; c += 16) {
      float t[16];
#pragma unroll
      for (int k = 0; k < 16; ++k) t[k] = b2d[c + k];
#pragma unroll
      for (int j = 0; j < 64; ++j) {
        const float h = h2[j];
#pragma unroll
        for (int k = 0; k < 16; ++k)
          t[k] = fmaf(h, W2d[j * 128 + c + k], t[k]);
      }
#pragma unroll
      for (int k = 0; k < 16; ++k) t[k] = fmaxf(t[k], 0.0f);  // ReLU on h3
#pragma unroll
      for (int k = 0; k < 16; ++k) {
        const float h = t[k];
#pragma unroll
        for (int o = 0; o < 64; ++o)
          h4[o] = fmaf(h, W3d[(c + k) * 64 + o], h4[o]);
      }
    }
    // ReLU on h4 — this was MISSING in R2 (the 0.17 absmax bug).
#pragma unroll
    for (int o = 0; o < 64; ++o) h4[o] = fmaxf(h4[o], 0.0f);
  }

  float h5[32];
  layer<64, 32, true>(W4 + d * 64 * 32, b4 + d * 32, h4, h5);
  float h6[16];
  layer<32, 16, true>(W5 + d * 32 * 16, b5 + d * 16, h5, h6);
  float h7[1];
  layer<16, 1, false>(W6 + d * 16, b6 + d, h6, h7);

  partial[d * BATCH + b] = h7[0];
}

__global__ __launch_bounds__(256) void reduce_kernel(
    const float* __restrict__ partial, float* __restrict__ out) {
  const int b = blockIdx.x * blockDim.x + threadIdx.x;
  float s = 0.0f;
#pragma unroll 8
  for (int d = 0; d < DIM; ++d) s += partial[d * BATCH + b];
  out[b] = s;
}

extern "C" void kernel_launch(void* const* d_in, const int* in_sizes, int n_in,
                              void* d_out, int out_size, void* d_ws, size_t ws_size,
                              hipStream_t stream) {
  const float* x = (const float*)d_in[0];
  const float* W[7];
  const float* B[7];
  for (int l = 0; l < 7; ++l) {
    W[l] = (const float*)d_in[1 + 2 * l];
    B[l] = (const float*)d_in[2 + 2 * l];
  }
  float* partial = (float*)d_ws;  // DIM * BATCH floats = 2 MB

  dim3 grid(DIM, BATCH / 256);
  mlp_kernel<<<grid, dim3(256), 0, stream>>>(
      x, W[0], B[0], W[1], B[1], W[2], B[2], W[3], B[3], W[4], B[4], W[5], B[5],
      W[6], B[6], partial);

  reduce_kernel<<<dim3(BATCH / 256), dim3(256), 0, stream>>>(partial,
                                                             (float*)d_out);
}

// Round 4
// 302.740 us; speedup vs baseline: 3.5138x; 2.5352x over previous
//
#include <hip/hip_runtime.h>

#define BATCH 2048
#define DIM   256

typedef __attribute__((ext_vector_type(8))) short short8;   // 8 x bf16 (4 VGPR)
typedef __attribute__((ext_vector_type(4))) float f32x4;    // MFMA acc

__device__ __forceinline__ short f32_to_bf16(float f) {
  unsigned u = __float_as_uint(f);
  unsigned r = u + 0x7fffu + ((u >> 16) & 1u);   // round-to-nearest-even
  return (short)(r >> 16);
}
__device__ __forceinline__ float bf16_to_f32(short h) {
  return __uint_as_float(((unsigned)(unsigned short)h) << 16);
}

// Split 8 fp32 into hi/lo bf16 fragments (fp32-equivalent when both used).
__device__ __forceinline__ void split8(const float* f, short8& hi, short8& lo) {
#pragma unroll
  for (int j = 0; j < 8; ++j) {
    short h = f32_to_bf16(f[j]);
    hi[j] = h;
    lo[j] = f32_to_bf16(f[j] - bf16_to_f32(h));
  }
}

// One MFMA layer FI->FO for a 16-row batch tile owned by one wave.
// A-frags (hi/lo) in, next layer's A-frags out via per-wave LDS transpose.
// Weights read from global in B-frag order: B[k][n], n=lane&15, k=quad*8+j.
template <int FI, int FO, bool EXTRACT>
__device__ __forceinline__ void mfma_layer(const float* __restrict__ Wl,
                                           const float* __restrict__ bl, int d,
                                           int lane, float* __restrict__ bw,
                                           short8* Ah, short8* Al) {
  const int m = lane & 15;   // A row / C col / B col
  const int q = lane >> 4;   // quad
  constexpr int KT = FI / 32;
  constexpr int NT = FO / 16;
#pragma unroll
  for (int nt = 0; nt < NT; ++nt) {
    const float bias = bl[d * FO + nt * 16 + m];          // per-col bias
    f32x4 acc = {bias, bias, bias, bias};
#pragma unroll
    for (int kt = 0; kt < KT; ++kt) {
      float wv[8];
      const float* Wp =
          Wl + (size_t)d * FI * FO + (size_t)(kt * 32 + q * 8) * FO + nt * 16 + m;
#pragma unroll
      for (int j = 0; j < 8; ++j) wv[j] = Wp[(size_t)j * FO];
      short8 Bh, Blo;
      split8(wv, Bh, Blo);
      acc = __builtin_amdgcn_mfma_f32_16x16x32_bf16(Ah[kt], Bh, acc, 0, 0, 0);
      acc = __builtin_amdgcn_mfma_f32_16x16x32_bf16(Al[kt], Bh, acc, 0, 0, 0);
      acc = __builtin_amdgcn_mfma_f32_16x16x32_bf16(Ah[kt], Blo, acc, 0, 0, 0);
    }
    // ReLU (all MFMA layers here have it) + write C tile to LDS (row-major,
    // stride 132 floats: 2-way-max bank aliasing, keeps b128 reads aligned).
#pragma unroll
    for (int r = 0; r < 4; ++r)
      bw[(q * 4 + r) * 132 + nt * 16 + m] = fmaxf(acc[r], 0.0f);
  }
  if (EXTRACT) {
    constexpr int KTn = FO / 32;
#pragma unroll
    for (int kt = 0; kt < KTn; ++kt) {
      const float* p = &bw[m * 132 + kt * 32 + q * 8];  // 16B-aligned
      float h[8];
      const f32x4 v0 = *(const f32x4*)p;
      const f32x4 v1 = *(const f32x4*)(p + 4);
#pragma unroll
      for (int j = 0; j < 4; ++j) { h[j] = v0[j]; h[4 + j] = v1[j]; }
      split8(h, Ah[kt], Al[kt]);
    }
  }
}

__global__ __launch_bounds__(256) void mlp_mfma(
    const float* __restrict__ x,
    const float* __restrict__ W0, const float* __restrict__ b0,
    const float* __restrict__ W1, const float* __restrict__ b1,
    const float* __restrict__ W2, const float* __restrict__ b2,
    const float* __restrict__ W3, const float* __restrict__ b3,
    const float* __restrict__ W4, const float* __restrict__ b4,
    const float* __restrict__ W5, const float* __restrict__ b5,
    const float* __restrict__ W6, const float* __restrict__ b6,
    float* __restrict__ partial) {
  const int lane = threadIdx.x & 63;
  const int wave = threadIdx.x >> 6;
  const int d = blockIdx.x;
  const int tile = blockIdx.y * 4 + wave;  // 0..127
  const int row0 = tile * 16;
  const int m = lane & 15;
  const int q = lane >> 4;

  __shared__ __align__(16) float buf[4][16 * 132];  // per-wave transpose tile
  float* bw = buf[wave];

  short8 Ah[4], Al[4];

  // L0: 1 -> 32 in VALU, producing L1's A-frags directly.
  {
    const float xv = x[(size_t)(row0 + m) * DIM + d];
    float h[8];
    const float* W = W0 + d * 32 + q * 8;
    const float* B = b0 + d * 32 + q * 8;
#pragma unroll
    for (int j = 0; j < 8; ++j) h[j] = fmaxf(fmaf(xv, W[j], B[j]), 0.0f);
    split8(h, Ah[0], Al[0]);
  }

  mfma_layer<32, 64, true>(W1, b1, d, lane, bw, Ah, Al);
  mfma_layer<64, 128, true>(W2, b2, d, lane, bw, Ah, Al);
  mfma_layer<128, 64, true>(W3, b3, d, lane, bw, Ah, Al);
  mfma_layer<64, 32, true>(W4, b4, d, lane, bw, Ah, Al);
  mfma_layer<32, 16, false>(W5, b5, d, lane, bw, Ah, Al);  // h6 left in LDS

  // L6: 16 -> 1. h6[row][c] in bw; out[row] = sum_c h6[row][c]*W6[d,c] + b6[d].
  {
    const float w6 = W6[d * 16 + m];
    const float bias6 = b6[d];
#pragma unroll
    for (int r = 0; r < 4; ++r) {
      float v = bw[(q * 4 + r) * 132 + m] * w6;
      v += __shfl_xor(v, 1);
      v += __shfl_xor(v, 2);
      v += __shfl_xor(v, 4);
      v += __shfl_xor(v, 8);
      if (m == 0) partial[(size_t)d * BATCH + row0 + q * 4 + r] = v + bias6;
    }
  }
}

__global__ __launch_bounds__(256) void reduce_kernel(
    const float* __restrict__ partial, float* __restrict__ out) {
  const int b = blockIdx.x * blockDim.x + threadIdx.x;
  float s = 0.0f;
#pragma unroll 8
  for (int d = 0; d < DIM; ++d) s += partial[(size_t)d * BATCH + b];
  out[b] = s;
}

extern "C" void kernel_launch(void* const* d_in, const int* in_sizes, int n_in,
                              void* d_out, int out_size, void* d_ws, size_t ws_size,
                              hipStream_t stream) {
  const float* x = (const float*)d_in[0];
  const float* W[7];
  const float* B[7];
  for (int l = 0; l < 7; ++l) {
    W[l] = (const float*)d_in[1 + 2 * l];
    B[l] = (const float*)d_in[2 + 2 * l];
  }
  float* partial = (float*)d_ws;  // DIM * BATCH floats = 2 MB

  dim3 grid(DIM, BATCH / 64);  // 256 d  x  32 row-chunks (4 waves * 16 rows)
  mlp_mfma<<<grid, dim3(256), 0, stream>>>(
      x, W[0], B[0], W[1], B[1], W[2], B[2], W[3], B[3], W[4], B[4], W[5], B[5],
      W[6], B[6], partial);

  reduce_kernel<<<dim3(BATCH / 256), dim3(256), 0, stream>>>(partial,
                                                             (float*)d_out);
}

// Round 5
// 211.406 us; speedup vs baseline: 5.0319x; 1.4320x over previous
//
#include <hip/hip_runtime.h>

#define BATCH 2048
#define DIM   256

typedef __attribute__((ext_vector_type(8))) short short8;   // 8 x bf16
typedef __attribute__((ext_vector_type(4))) float f32x4;

// Packed-weight tile table (layers 1..5 of the MLP):
// (FI,FO): (32,64) (64,128) (128,64) (64,32) (32,16)
// KT=FI/32, NT=FO/16, tiles=KT*NT: 4, 16, 16, 4, 1  -> bases 0,4,20,36,40
#define NTILES 41
#define TILE_SHORTS 1024   // 64 lanes * 8 bf16 * (hi+lo) = 2 KB
#define PART_FLOATS (BATCH * DIM)
#define PACK_OFF_BYTES (PART_FLOATS * 4)   // partial buffer first (2 MB)

__device__ __forceinline__ short f32_to_bf16(float f) {
  unsigned u = __float_as_uint(f);
  unsigned r = u + 0x7fffu + ((u >> 16) & 1u);   // RNE
  return (short)(r >> 16);
}
__device__ __forceinline__ float bf16_to_f32(short h) {
  return __uint_as_float(((unsigned)(unsigned short)h) << 16);
}
__device__ __forceinline__ void split8(const float* f, short8& hi, short8& lo) {
#pragma unroll
  for (int j = 0; j < 8; ++j) {
    short h = f32_to_bf16(f[j]);
    hi[j] = h;
    lo[j] = f32_to_bf16(f[j] - bf16_to_f32(h));
  }
}

// ---- prep: pack W1..W5 into B-frag order, split into bf16 hi/lo ----
// Frag element for lane(m=lane&15,q=lane>>4), j: W[d][kt*32+q*8+j][nt*16+m]
__global__ __launch_bounds__(256) void prep_kernel(
    const float* __restrict__ W1, const float* __restrict__ W2,
    const float* __restrict__ W3, const float* __restrict__ W4,
    const float* __restrict__ W5, short* __restrict__ pack) {
  const int d = blockIdx.x;
  for (int job = threadIdx.x; job < NTILES * 64; job += 256) {
    const int tile = job >> 6, lane = job & 63;
    const int m = lane & 15, q = lane >> 4;
    const float* W; int FI, FO, lt;
    if (tile < 4)       { W = W1; FI = 32;  FO = 64;  lt = tile; }
    else if (tile < 20) { W = W2; FI = 64;  FO = 128; lt = tile - 4; }
    else if (tile < 36) { W = W3; FI = 128; FO = 64;  lt = tile - 20; }
    else if (tile < 40) { W = W4; FI = 64;  FO = 32;  lt = tile - 36; }
    else                { W = W5; FI = 32;  FO = 16;  lt = 0; }
    const int KT = FI >> 5;
    const int nt = lt / KT, kt = lt - nt * KT;
    const float* Wp = W + (size_t)d * FI * FO +
                      (size_t)(kt * 32 + q * 8) * FO + nt * 16 + m;
    float wv[8];
#pragma unroll
    for (int j = 0; j < 8; ++j) wv[j] = Wp[(size_t)j * FO];
    short8 hi, lo;
    split8(wv, hi, lo);
    short* base = pack + (size_t)(d * NTILES + tile) * TILE_SHORTS;
    *(short8*)(base + lane * 8) = hi;
    *(short8*)(base + 512 + lane * 8) = lo;
  }
}

// ---- one MFMA layer for 2 row-tiles (M=32) owned by one wave ----
// A/B both hi/lo-split (3 MFMAs) -> fp32-equivalent accuracy.
// C pairs (32 cols) round-trip through a small per-wave 16x36 LDS buffer to
// become next layer's A-frags (write pattern: 2-way bank alias = free).
template <int FI, int FO, int LBASE, bool EXTRACT>
__device__ __forceinline__ void layer_mfma(
    const short* __restrict__ packd, const float* __restrict__ bld,
    int m, int q, int lane, float* __restrict__ bw,  // [2][16*36]
    const short8 (*Ah)[4], const short8 (*Al)[4],
    short8 (*Oh)[4], short8 (*Ol)[4]) {
  constexpr int KT = FI / 32, NT = FO / 16;
#pragma unroll
  for (int nt = 0; nt < NT; ++nt) {
    const float bias = bld[nt * 16 + m];
    f32x4 acc0 = {bias, bias, bias, bias};
    f32x4 acc1 = acc0;
#pragma unroll
    for (int kt = 0; kt < KT; ++kt) {
      const short* tb = packd + (size_t)(LBASE + nt * KT + kt) * TILE_SHORTS;
      const short8 Bh = *(const short8*)(tb + lane * 8);
      const short8 Bl = *(const short8*)(tb + 512 + lane * 8);
      acc0 = __builtin_amdgcn_mfma_f32_16x16x32_bf16(Ah[0][kt], Bh, acc0, 0, 0, 0);
      acc0 = __builtin_amdgcn_mfma_f32_16x16x32_bf16(Al[0][kt], Bh, acc0, 0, 0, 0);
      acc0 = __builtin_amdgcn_mfma_f32_16x16x32_bf16(Ah[0][kt], Bl, acc0, 0, 0, 0);
      acc1 = __builtin_amdgcn_mfma_f32_16x16x32_bf16(Ah[1][kt], Bh, acc1, 0, 0, 0);
      acc1 = __builtin_amdgcn_mfma_f32_16x16x32_bf16(Al[1][kt], Bh, acc1, 0, 0, 0);
      acc1 = __builtin_amdgcn_mfma_f32_16x16x32_bf16(Ah[1][kt], Bl, acc1, 0, 0, 0);
    }
    const int hcol = (nt & 1) * 16 + m;   // column within the 32-col pair
#pragma unroll
    for (int r = 0; r < 4; ++r) {
      bw[0 * 576 + (q * 4 + r) * 36 + hcol] = fmaxf(acc0[r], 0.0f);  // ReLU
      bw[1 * 576 + (q * 4 + r) * 36 + hcol] = fmaxf(acc1[r], 0.0f);
    }
    if (EXTRACT && (nt & 1)) {           // pair complete -> next A-frag ktn
      const int ktn = nt >> 1;
#pragma unroll
      for (int rt = 0; rt < 2; ++rt) {
        const float* p = &bw[rt * 576 + m * 36 + q * 8];  // 16B-aligned
        const f32x4 v0 = *(const f32x4*)p;
        const f32x4 v1 = *(const f32x4*)(p + 4);
        float h[8];
#pragma unroll
        for (int j = 0; j < 4; ++j) { h[j] = v0[j]; h[4 + j] = v1[j]; }
        split8(h, Oh[rt][ktn], Ol[rt][ktn]);
      }
    }
  }
}

__global__ __launch_bounds__(256) void mlp_mfma(
    const float* __restrict__ x,
    const float* __restrict__ W0, const float* __restrict__ b0,
    const float* __restrict__ b1, const float* __restrict__ b2,
    const float* __restrict__ b3, const float* __restrict__ b4,
    const float* __restrict__ b5,
    const float* __restrict__ W6, const float* __restrict__ b6,
    const short* __restrict__ pack, float* __restrict__ partial) {
  const int lane = threadIdx.x & 63;
  const int wave = threadIdx.x >> 6;
  const int m = lane & 15, q = lane >> 4;
  const int d = blockIdx.x;
  const int row0 = blockIdx.y * 128 + wave * 32;   // 32 rows per wave

  __shared__ __align__(16) float buf[4][2 * 576];  // per-wave, no barriers
  float* bw = buf[wave];
  const short* packd = pack + (size_t)d * NTILES * TILE_SHORTS;

  short8 A0h[2][4], A0l[2][4], A1h[2][4], A1l[2][4];

  // L0: 1 -> 32 in VALU (wave-uniform scalar weights), makes L1 A-frags.
#pragma unroll
  for (int rt = 0; rt < 2; ++rt) {
    const float xv = x[(size_t)(row0 + rt * 16 + m) * DIM + d];
    float h[8];
#pragma unroll
    for (int j = 0; j < 8; ++j)
      h[j] = fmaxf(fmaf(xv, W0[d * 32 + q * 8 + j], b0[d * 32 + q * 8 + j]), 0.0f);
    split8(h, A0h[rt][0], A0l[rt][0]);
  }

  layer_mfma<32, 64, 0, true>(packd, b1 + d * 64, m, q, lane, bw, A0h, A0l, A1h, A1l);
  layer_mfma<64, 128, 4, true>(packd, b2 + d * 128, m, q, lane, bw, A1h, A1l, A0h, A0l);
  layer_mfma<128, 64, 20, true>(packd, b3 + d * 64, m, q, lane, bw, A0h, A0l, A1h, A1l);
  layer_mfma<64, 32, 36, true>(packd, b4 + d * 32, m, q, lane, bw, A1h, A1l, A0h, A0l);
  layer_mfma<32, 16, 40, false>(packd, b5 + d * 16, m, q, lane, bw, A0h, A0l, A1h, A1l);

  // L6: 16 -> 1. h6 sits in bw (cols 0..15). out[row] = sum_c h6*W6 + b6.
  {
    const float w6 = W6[d * 16 + m];
    const float bias6 = b6[d];
#pragma unroll
    for (int rt = 0; rt < 2; ++rt) {
#pragma unroll
      for (int r = 0; r < 4; ++r) {
        float v = bw[rt * 576 + (q * 4 + r) * 36 + m] * w6;
        v += __shfl_xor(v, 1);
        v += __shfl_xor(v, 2);
        v += __shfl_xor(v, 4);
        v += __shfl_xor(v, 8);
        if (m == 0)
          partial[(size_t)d * BATCH + row0 + rt * 16 + q * 4 + r] = v + bias6;
      }
    }
  }
}

__global__ __launch_bounds__(256) void reduce_kernel(
    const float* __restrict__ partial, float* __restrict__ out) {
  const int b = blockIdx.x * blockDim.x + threadIdx.x;
  float s = 0.0f;
#pragma unroll 8
  for (int d = 0; d < DIM; ++d) s += partial[(size_t)d * BATCH + b];
  out[b] = s;
}

extern "C" void kernel_launch(void* const* d_in, const int* in_sizes, int n_in,
                              void* d_out, int out_size, void* d_ws, size_t ws_size,
                              hipStream_t stream) {
  const float* x = (const float*)d_in[0];
  const float* W[7];
  const float* B[7];
  for (int l = 0; l < 7; ++l) {
    W[l] = (const float*)d_in[1 + 2 * l];
    B[l] = (const float*)d_in[2 + 2 * l];
  }
  float* partial = (float*)d_ws;                       // 2 MB
  short* pack = (short*)((char*)d_ws + PACK_OFF_BYTES); // 21.5 MB

  prep_kernel<<<dim3(DIM), dim3(256), 0, stream>>>(W[1], W[2], W[3], W[4],
                                                   W[5], pack);

  mlp_mfma<<<dim3(DIM, BATCH / 128), dim3(256), 0, stream>>>(
      x, W[0], B[0], B[1], B[2], B[3], B[4], B[5], W[6], B[6], pack, partial);

  reduce_kernel<<<dim3(BATCH / 256), dim3(256), 0, stream>>>(partial,
                                                             (float*)d_out);
}

// Round 6
// 179.318 us; speedup vs baseline: 5.9323x; 1.1789x over previous
//
#include <hip/hip_runtime.h>

#define BATCH 2048
#define DIM   256

typedef _Float16 half8 __attribute__((ext_vector_type(8)));  // 8 x f16 (4 VGPR)
typedef __attribute__((ext_vector_type(4))) float f32x4;

// Packed-weight tile table (layers 1..5):
// (FI,FO): (32,64) (64,128) (128,64) (64,32) (32,16)
// KT=FI/32, NT=FO/16, tiles=KT*NT: 4, 16, 16, 4, 1 -> bases 0,4,20,36,40
#define NTILES 41
#define TILE_HALVES 1024   // 64 lanes * 8 f16 * (hi+lo) = 2 KB
#define PACK_OFF_BYTES (BATCH * DIM * 4)   // partial buffer first (2 MB)

__device__ __forceinline__ void cvt8(const float* f, half8& h) {
#pragma unroll
  for (int j = 0; j < 8; ++j) h[j] = (_Float16)f[j];
}

// ---- prep: LDS-staged transpose of W1..W5 into B-frag order, f16 hi/lo ----
template <int FI, int FO, int BASE>
__device__ __forceinline__ void prep_layer(const float* __restrict__ W, int d,
                                           int t, float* __restrict__ sw,
                                           _Float16* __restrict__ pack) {
  const float* Wd = W + (size_t)d * FI * FO;
  // coalesced float4 stage into LDS
#pragma unroll 4
  for (int i = t; i < FI * FO / 4; i += 256)
    ((f32x4*)sw)[i] = ((const f32x4*)Wd)[i];
  __syncthreads();
  constexpr int KT = FI / 32, NT = FO / 16, T = KT * NT;
  for (int job = t; job < T * 64; job += 256) {
    const int tile = job >> 6, lane = job & 63;
    const int m = lane & 15, q = lane >> 4;
    const int nt = tile / KT, kt = tile % KT;   // matches main's nt*KT+kt
    float wv[8];
#pragma unroll
    for (int j = 0; j < 8; ++j)
      wv[j] = sw[(kt * 32 + q * 8 + j) * FO + nt * 16 + m];
    half8 hi, lo;
#pragma unroll
    for (int j = 0; j < 8; ++j) {
      _Float16 h = (_Float16)wv[j];
      hi[j] = h;
      lo[j] = (_Float16)(wv[j] - (float)h);
    }
    _Float16* base = pack + (size_t)(d * NTILES + BASE + tile) * TILE_HALVES;
    *(half8*)(base + lane * 8) = hi;
    *(half8*)(base + 512 + lane * 8) = lo;
  }
  __syncthreads();
}

__global__ __launch_bounds__(256) void prep_kernel(
    const float* __restrict__ W1, const float* __restrict__ W2,
    const float* __restrict__ W3, const float* __restrict__ W4,
    const float* __restrict__ W5, _Float16* __restrict__ pack) {
  __shared__ float sw[64 * 128];   // 32 KB, max layer
  const int d = blockIdx.x, t = threadIdx.x;
  prep_layer<32, 64, 0>(W1, d, t, sw, pack);
  prep_layer<64, 128, 4>(W2, d, t, sw, pack);
  prep_layer<128, 64, 20>(W3, d, t, sw, pack);
  prep_layer<64, 32, 36>(W4, d, t, sw, pack);
  prep_layer<32, 16, 40>(W5, d, t, sw, pack);
}

// ---- one MFMA layer for 2 row-tiles (M=32) owned by one wave ----
// A = f16 activations (hi only), B = f16 hi+lo weights -> 2 MFMAs per tile.
template <int FI, int FO, int LBASE, bool EXTRACT>
__device__ __forceinline__ void layer_mfma(
    const _Float16* __restrict__ packd, const float* __restrict__ bld,
    int m, int q, int lane, float* __restrict__ bw,  // [2][16*36]
    const half8* A, half8* O) {
  constexpr int KT = FI / 32, NT = FO / 16;
#pragma unroll
  for (int nt = 0; nt < NT; ++nt) {
    const float bias = bld[nt * 16 + m];
    f32x4 acc0 = {bias, bias, bias, bias};
    f32x4 acc1 = acc0;
#pragma unroll
    for (int kt = 0; kt < KT; ++kt) {
      const _Float16* tb = packd + (size_t)(LBASE + nt * KT + kt) * TILE_HALVES;
      const half8 Bh = *(const half8*)(tb + lane * 8);
      const half8 Bl = *(const half8*)(tb + 512 + lane * 8);
      acc0 = __builtin_amdgcn_mfma_f32_16x16x32_f16(A[0 * 4 + kt], Bh, acc0, 0, 0, 0);
      acc0 = __builtin_amdgcn_mfma_f32_16x16x32_f16(A[0 * 4 + kt], Bl, acc0, 0, 0, 0);
      acc1 = __builtin_amdgcn_mfma_f32_16x16x32_f16(A[1 * 4 + kt], Bh, acc1, 0, 0, 0);
      acc1 = __builtin_amdgcn_mfma_f32_16x16x32_f16(A[1 * 4 + kt], Bl, acc1, 0, 0, 0);
    }
    const int hcol = (nt & 1) * 16 + m;
#pragma unroll
    for (int r = 0; r < 4; ++r) {
      bw[0 * 576 + (q * 4 + r) * 36 + hcol] = fmaxf(acc0[r], 0.0f);  // ReLU
      bw[1 * 576 + (q * 4 + r) * 36 + hcol] = fmaxf(acc1[r], 0.0f);
    }
    if (EXTRACT && (nt & 1)) {  // 32-col pair complete -> next A-frag ktn
      const int ktn = nt >> 1;
#pragma unroll
      for (int rt = 0; rt < 2; ++rt) {
        const float* p = &bw[rt * 576 + m * 36 + q * 8];  // 16B-aligned
        const f32x4 v0 = *(const f32x4*)p;
        const f32x4 v1 = *(const f32x4*)(p + 4);
        float h[8];
#pragma unroll
        for (int j = 0; j < 4; ++j) { h[j] = v0[j]; h[4 + j] = v1[j]; }
        cvt8(h, O[rt * 4 + ktn]);
      }
    }
  }
}

__global__ __launch_bounds__(256) void mlp_mfma(
    const float* __restrict__ x,
    const float* __restrict__ W0, const float* __restrict__ b0,
    const float* __restrict__ b1, const float* __restrict__ b2,
    const float* __restrict__ b3, const float* __restrict__ b4,
    const float* __restrict__ b5,
    const float* __restrict__ W6, const float* __restrict__ b6,
    const _Float16* __restrict__ pack, float* __restrict__ partial) {
  const int lane = threadIdx.x & 63;
  const int wave = threadIdx.x >> 6;
  const int m = lane & 15, q = lane >> 4;
  const int d = blockIdx.x;
  const int row0 = blockIdx.y * 128 + wave * 32;  // 32 rows per wave

  __shared__ __align__(16) float buf[4][2 * 576];  // per-wave, no barriers
  float* bw = buf[wave];
  const _Float16* packd = pack + (size_t)d * NTILES * TILE_HALVES;

  half8 A0[2 * 4], A1[2 * 4];

  // L0: 1 -> 32 in VALU (wave-uniform scalar weights) -> L1 A-frags.
#pragma unroll
  for (int rt = 0; rt < 2; ++rt) {
    const float xv = x[(size_t)(row0 + rt * 16 + m) * DIM + d];
    float h[8];
#pragma unroll
    for (int j = 0; j < 8; ++j)
      h[j] = fmaxf(fmaf(xv, W0[d * 32 + q * 8 + j], b0[d * 32 + q * 8 + j]), 0.0f);
    cvt8(h, A0[rt * 4 + 0]);
  }

  layer_mfma<32, 64, 0, true>(packd, b1 + d * 64, m, q, lane, bw, A0, A1);
  layer_mfma<64, 128, 4, true>(packd, b2 + d * 128, m, q, lane, bw, A1, A0);
  layer_mfma<128, 64, 20, true>(packd, b3 + d * 64, m, q, lane, bw, A0, A1);
  layer_mfma<64, 32, 36, true>(packd, b4 + d * 32, m, q, lane, bw, A1, A0);
  layer_mfma<32, 16, 40, false>(packd, b5 + d * 16, m, q, lane, bw, A0, A1);

  // L6: 16 -> 1 from LDS; shuffle-reduce 16 cols.
  {
    const float w6 = W6[d * 16 + m];
    const float bias6 = b6[d];
#pragma unroll
    for (int rt = 0; rt < 2; ++rt) {
#pragma unroll
      for (int r = 0; r < 4; ++r) {
        float v = bw[rt * 576 + (q * 4 + r) * 36 + m] * w6;
        v += __shfl_xor(v, 1);
        v += __shfl_xor(v, 2);
        v += __shfl_xor(v, 4);
        v += __shfl_xor(v, 8);
        if (m == 0)
          partial[(size_t)d * BATCH + row0 + rt * 16 + q * 4 + r] = v + bias6;
      }
    }
  }
}

__global__ __launch_bounds__(256) void reduce_kernel(
    const float* __restrict__ partial, float* __restrict__ out) {
  const int b = blockIdx.x * blockDim.x + threadIdx.x;
  float s = 0.0f;
#pragma unroll 8
  for (int d = 0; d < DIM; ++d) s += partial[(size_t)d * BATCH + b];
  out[b] = s;
}

extern "C" void kernel_launch(void* const* d_in, const int* in_sizes, int n_in,
                              void* d_out, int out_size, void* d_ws, size_t ws_size,
                              hipStream_t stream) {
  const float* x = (const float*)d_in[0];
  const float* W[7];
  const float* B[7];
  for (int l = 0; l < 7; ++l) {
    W[l] = (const float*)d_in[1 + 2 * l];
    B[l] = (const float*)d_in[2 + 2 * l];
  }
  float* partial = (float*)d_ws;                            // 2 MB
  _Float16* pack = (_Float16*)((char*)d_ws + PACK_OFF_BYTES);  // 21 MB

  prep_kernel<<<dim3(DIM), dim3(256), 0, stream>>>(W[1], W[2], W[3], W[4],
                                                   W[5], pack);

  mlp_mfma<<<dim3(DIM, BATCH / 128), dim3(256), 0, stream>>>(
      x, W[0], B[0], B[1], B[2], B[3], B[4], B[5], W[6], B[6], pack, partial);

  reduce_kernel<<<dim3(BATCH / 256), dim3(256), 0, stream>>>(partial,
                                                             (float*)d_out);
}